// Round 2
// baseline (470.231 us; speedup 1.0000x reference)
//
#include <hip/hip_runtime.h>
#include <hip/hip_bf16.h>

// EdgeConv, algebraically simplified:
//   out[p,o] = sum_c (t[p,c]/K - x[p,c])*W[o,c] + sum_c x[p,c]*W[o,64+c] + b[o]
//   t[p,c]   = sum_{k=0..19} g_flat[p, 20c+k],  g_flat[p,j] = x[b, adj[p,j>>6], j&63]
// R2: W as 64 packed-bf16 VGPRs (was 128 f32 -> AGPR demotion), no LDS W stage,
//     no __syncthreads (wave-private LDS only) -> 16 waves/CU vs 8.

namespace {
constexpr int B_    = 4;
constexpr int N_    = 32768;
constexpr int K_    = 20;
constexpr int C_    = 64;
constexpr int O_    = 64;
constexpr int PTOT  = B_ * N_;       // 131072 points
constexpr int BLOCK = 256;           // 4 waves
constexpr int WPB   = 4;
constexpr int GRID  = 1024;          // 4096 waves -> 32 points/wave
}

// wave-private LDS producer->consumer fence (same-wave DS ops are in order;
// drain outstanding LDS/vmem-lgkm ops, pin compiler ordering)
#define WAVE_LDS_FENCE() do {                                  \
    asm volatile("s_waitcnt lgkmcnt(0)" ::: "memory");         \
    __builtin_amdgcn_wave_barrier();                           \
  } while (0)

__global__ __launch_bounds__(BLOCK, 4) void edgeconv_kernel(
    const float* __restrict__ x,     // (B,N,C)
    const int*   __restrict__ adj,   // (B,N,K)
    const float* __restrict__ W,     // (O, 2C)
    const float* __restrict__ bias,  // (O,)
    float*       __restrict__ out)   // (B,N,O)
{
  __shared__ __align__(16) float win[WPB][K_ * C_];   // 4 * 5120 B
  __shared__ __align__(16) float buf[WPB][2 * C_];    // 4 * 512 B

  const int lane = threadIdx.x & 63;
  const int wid  = __builtin_amdgcn_readfirstlane((int)(threadIdx.x >> 6));

  // ---- W[lane][0..127] -> 64 packed bf16 pairs in VGPRs (one-time; L1/L2-cached)
  unsigned int wp[64];
  {
    const float4* wrow = reinterpret_cast<const float4*>(W + lane * 2 * C_);
#pragma unroll
    for (int i = 0; i < 32; ++i) {
      const float4 f = wrow[i];
      __hip_bfloat162 h0 = __float22bfloat162_rn(make_float2(f.x, f.y));
      __hip_bfloat162 h1 = __float22bfloat162_rn(make_float2(f.z, f.w));
      wp[2 * i + 0] = *reinterpret_cast<unsigned int*>(&h0);  // .x in low 16
      wp[2 * i + 1] = *reinterpret_cast<unsigned int*>(&h1);
    }
  }
  const float bl = bias[lane];

  float* mywin = win[wid];
  float* mybuf = buf[wid];

  for (int p = blockIdx.x * WPB + wid; p < PTOT; p += GRID * WPB) {
    const int b = p >> 15;                        // p / N
    const float* xb   = x + (size_t)b * N_ * C_;
    const int*   arow = adj + (size_t)p * K_;     // wave-uniform -> s_loads

    // gather: 20 independent coalesced 256B row loads, lane = channel
    float vals[K_];
#pragma unroll
    for (int k = 0; k < K_; ++k) {
      const int idx = arow[k];                    // SGPR
      vals[k] = xb[idx * C_ + lane];
    }
    const float xv = x[(size_t)p * C_ + lane];

#pragma unroll
    for (int k = 0; k < K_; ++k)
      mywin[k * C_ + lane] = vals[k];             // conflict-free writes
    WAVE_LDS_FENCE();

    // window sum: lane c reads flat[20c .. 20c+19] as 5x float4 (16B-aligned,
    // banks evenly spread -> no extra conflicts)
    const float4* wptr = reinterpret_cast<const float4*>(mywin + lane * K_);
    float t = 0.f;
#pragma unroll
    for (int s = 0; s < 5; ++s) {
      const float4 v = wptr[s];
      t += (v.x + v.y) + (v.z + v.w);
    }

    mybuf[lane]      = t * (1.f / K_) - xv;       // a[c]
    mybuf[C_ + lane] = xv;                        // x[c]
    WAVE_LDS_FENCE();

    // matvec: out[o] = sum_j buf[j] * W[o][j], W unpacked from bf16 pairs
    float acc0 = 0.f, acc1 = 0.f, acc2 = 0.f, acc3 = 0.f;
    const float4* bp = reinterpret_cast<const float4*>(mybuf);
#pragma unroll
    for (int i = 0; i < 32; ++i) {
      const float4 v = bp[i];                     // LDS broadcast read
      const unsigned int u0 = wp[2 * i + 0];
      const unsigned int u1 = wp[2 * i + 1];
      const float w0 = __uint_as_float(u0 << 16);
      const float w1 = __uint_as_float(u0 & 0xFFFF0000u);
      const float w2 = __uint_as_float(u1 << 16);
      const float w3 = __uint_as_float(u1 & 0xFFFF0000u);
      acc0 = fmaf(v.x, w0, acc0);
      acc1 = fmaf(v.y, w1, acc1);
      acc2 = fmaf(v.z, w2, acc2);
      acc3 = fmaf(v.w, w3, acc3);
    }

    out[(size_t)p * O_ + lane] = ((acc0 + acc1) + (acc2 + acc3)) + bl;
  }
}

extern "C" void kernel_launch(void* const* d_in, const int* in_sizes, int n_in,
                              void* d_out, int out_size, void* d_ws, size_t ws_size,
                              hipStream_t stream) {
  const float* x    = (const float*)d_in[0];
  const int*   adj  = (const int*)d_in[1];
  const float* W    = (const float*)d_in[2];
  const float* bias = (const float*)d_in[3];
  float* out = (float*)d_out;

  hipLaunchKernelGGL(edgeconv_kernel, dim3(GRID), dim3(BLOCK), 0, stream,
                     x, adj, W, bias, out);
}

// Round 4
// 370.303 us; speedup vs baseline: 1.2699x; 1.2699x over previous
//
#include <hip/hip_runtime.h>

// EdgeConv, algebraically simplified:
//   out[p,o] = sum_c (t[p,c]/K - x[p,c])*W[o,c] + sum_c x[p,c]*W[o,64+c] + b[o]
//   t[p,c]   = sum_{k=0..19} g_flat[p, 20c+k],  g_flat[p,j] = x[b, adj[p,j>>6], j&63]
// R3b: W as 64 packed-f16 VGPRs filled via aliased LDS stage (no spill, no
//      permanent wstage); gather via global_load_lds (no vals[] regs, no
//      ds_write); v_dot2_f32_f16 matvec; XCD<->batch partition for L2 locality.
//      (R3 fix: half2_t must be __fp16-based to match cvt_pkrtz/fdot2.)

typedef __fp16 half2_t __attribute__((ext_vector_type(2)));
typedef unsigned int u32;

#if __has_builtin(__builtin_amdgcn_fdot2)
#define FDOT2(a, b, c) __builtin_amdgcn_fdot2((a), (b), (c), false)
#else
#define FDOT2(a, b, c) fmaf((float)(a).x, (float)(b).x, fmaf((float)(a).y, (float)(b).y, (c)))
#endif

namespace {
constexpr int B_    = 4;
constexpr int N_    = 32768;
constexpr int K_    = 20;
constexpr int C_    = 64;
constexpr int O_    = 64;
constexpr int BLOCK = 256;           // 4 waves
constexpr int WPB   = 4;
constexpr int GRID  = 1024;          // 4096 waves, 32 points/wave
constexpr int WROW  = 132;           // padded W row stride in LDS stage (floats)
constexpr int WIN   = K_ * C_;       // 1280 floats per-wave window
}

__global__ __launch_bounds__(BLOCK, 4) void edgeconv_kernel(
    const float* __restrict__ x,     // (B,N,C)
    const int*   __restrict__ adj,   // (B,N,K)
    const float* __restrict__ W,     // (O, 2C)
    const float* __restrict__ bias,  // (O,)
    float*       __restrict__ out)   // (B,N,O)
{
  // Union: prologue uses smem as wstage[64*132] (33792 B, coalesced W stage);
  // steady state reuses the same memory as win[4][1280] + buf[4][128] (22528 B).
  __shared__ __align__(16) float smem[O_ * WROW];   // 8448 floats

  const int lane = threadIdx.x & 63;
  const int wid  = __builtin_amdgcn_readfirstlane((int)(threadIdx.x >> 6));

  // ---- prologue: coalesced W -> LDS stage -> 64 packed-f16 VGPRs per lane
  for (int i = threadIdx.x; i < O_ * 2 * C_; i += BLOCK) {
    smem[(i >> 7) * WROW + (i & 127)] = W[i];
  }
  __syncthreads();

  half2_t wp[64];                    // lane o holds W[o][0..127] as 64 f16 pairs
  {
    const float* wrow = smem + lane * WROW;
#pragma unroll 2
    for (int i = 0; i < 64; ++i) {
      wp[i] = __builtin_amdgcn_cvt_pkrtz(wrow[2 * i], wrow[2 * i + 1]);
    }
  }
  const float bl = bias[lane];
  __syncthreads();                   // everyone done reading wstage

  float* win = smem;                       // [WPB][WIN]
  float* buf = smem + WPB * WIN;           // [WPB][2*C_]
  float* mywin = win + wid * WIN;
  float* mybuf = buf + wid * 2 * C_;
  auto ldsw = (__attribute__((address_space(3))) u32*)mywin;

  // XCD<->batch partition: blocks with same blockIdx%8 land on the same XCD;
  // give each XCD one batch (2 XCD-slots per batch) -> 8 MB L2 working set.
  const int xslot = blockIdx.x & 7;
  const int batch = xslot >> 1;                         // 0..3
  const int group = ((blockIdx.x >> 3) << 1) | (xslot & 1);   // 0..255
  const float* xb = x + (size_t)batch * (N_ * C_);

  for (int it = 0; it < 32; ++it) {
    const int n = group * WPB + wid + it * 1024;        // 0..32767, exact cover
    const int p = batch * N_ + n;
    const int* arow = adj + (size_t)p * K_;             // wave-uniform -> s_load

    // gather: 20 coalesced 256B rows DMA'd straight into LDS (base + lane*4)
#pragma unroll
    for (int k = 0; k < K_; ++k) {
      const int idx = arow[k];                          // SGPR
      const float* src = xb + idx * C_ + lane;
      __builtin_amdgcn_global_load_lds(
          (const __attribute__((address_space(1))) u32*)src,
          ldsw + k * C_, 4, 0, 0);
    }
    const float xv = xb[n * C_ + lane];

    asm volatile("s_waitcnt vmcnt(0)" ::: "memory");    // per-wave DMA drain
    __builtin_amdgcn_wave_barrier();

    // window sum: lane c reads flat[20c..20c+19] as 5x float4 (16B aligned)
    const float4* wq = reinterpret_cast<const float4*>(mywin + lane * K_);
    float t = 0.f;
#pragma unroll
    for (int s = 0; s < 5; ++s) {
      const float4 v = wq[s];
      t += (v.x + v.y) + (v.z + v.w);
    }

    mybuf[lane]      = t * (1.f / K_) - xv;             // a[c]
    mybuf[C_ + lane] = xv;                              // x[c]
    asm volatile("s_waitcnt lgkmcnt(0)" ::: "memory");
    __builtin_amdgcn_wave_barrier();

    // matvec: out[o] = sum_j buf[j]*W[o][j], via v_dot2_f32_f16
    float acc0 = 0.f, acc1 = 0.f, acc2 = 0.f, acc3 = 0.f;
    const float4* bp = reinterpret_cast<const float4*>(mybuf);
#pragma unroll
    for (int i = 0; i < 32; i += 2) {
      const float4 v0 = bp[i], v1 = bp[i + 1];          // LDS broadcast reads
      const half2_t p0 = __builtin_amdgcn_cvt_pkrtz(v0.x, v0.y);
      const half2_t p1 = __builtin_amdgcn_cvt_pkrtz(v0.z, v0.w);
      const half2_t p2 = __builtin_amdgcn_cvt_pkrtz(v1.x, v1.y);
      const half2_t p3 = __builtin_amdgcn_cvt_pkrtz(v1.z, v1.w);
      acc0 = FDOT2(p0, wp[2 * i + 0], acc0);
      acc1 = FDOT2(p1, wp[2 * i + 1], acc1);
      acc2 = FDOT2(p2, wp[2 * i + 2], acc2);
      acc3 = FDOT2(p3, wp[2 * i + 3], acc3);
    }

    out[(size_t)p * O_ + lane] = ((acc0 + acc1) + (acc2 + acc3)) + bl;
  }
}

extern "C" void kernel_launch(void* const* d_in, const int* in_sizes, int n_in,
                              void* d_out, int out_size, void* d_ws, size_t ws_size,
                              hipStream_t stream) {
  const float* x    = (const float*)d_in[0];
  const int*   adj  = (const int*)d_in[1];
  const float* W    = (const float*)d_in[2];
  const float* bias = (const float*)d_in[3];
  float* out = (float*)d_out;

  hipLaunchKernelGGL(edgeconv_kernel, dim3(GRID), dim3(BLOCK), 0, stream,
                     x, adj, W, bias, out);
}

// Round 5
// 162.046 us; speedup vs baseline: 2.9018x; 2.2852x over previous
//
#include <hip/hip_runtime.h>

// EdgeConv, algebraically simplified:
//   out[p,o] = sum_c (t[p,c]/K - x[p,c])*W[o,c] + sum_c x[p,c]*W[o,64+c] + b[o]
//   t[p,c]   = sum_{k=0..19} g_flat[p, 20c+k],  g_flat[p,j] = x[b, adj[p,j>>6], j&63]
// R4: fix the scratch spill — W fill loop FULLY unrolled (constant indices so
//     wp[64] stays in registers; R3b's "#pragma unroll 2" forced dynamic
//     indexing -> scratch -> 900 MB of spill traffic). launch_bounds(256,3)
//     gives the allocator ~168 regs. GRID=4096 (8 pts/wave) avoids the
//     persistent-block serialization cliff at 3 blocks/CU.

typedef __fp16 half2_t __attribute__((ext_vector_type(2)));
typedef unsigned int u32;

#if __has_builtin(__builtin_amdgcn_fdot2)
#define FDOT2(a, b, c) __builtin_amdgcn_fdot2((a), (b), (c), false)
#else
#define FDOT2(a, b, c) fmaf((float)(a).x, (float)(b).x, fmaf((float)(a).y, (float)(b).y, (c)))
#endif

namespace {
constexpr int B_    = 4;
constexpr int N_    = 32768;
constexpr int K_    = 20;
constexpr int C_    = 64;
constexpr int O_    = 64;
constexpr int BLOCK = 256;           // 4 waves
constexpr int WPB   = 4;
constexpr int GRID  = 4096;          // 16384 waves, 8 points/wave
constexpr int ITERS = 8;
constexpr int WROW  = 132;           // padded W row stride in LDS stage (floats)
constexpr int WIN   = K_ * C_;       // 1280 floats per-wave window
}

__global__ __launch_bounds__(BLOCK, 3) void edgeconv_kernel(
    const float* __restrict__ x,     // (B,N,C)
    const int*   __restrict__ adj,   // (B,N,K)
    const float* __restrict__ W,     // (O, 2C)
    const float* __restrict__ bias,  // (O,)
    float*       __restrict__ out)   // (B,N,O)
{
  // Union: prologue uses smem as wstage[64*132] (33792 B, coalesced W stage);
  // steady state reuses it as win[4][1280] + buf[4][128] (22528 B).
  __shared__ __align__(16) float smem[O_ * WROW];   // 8448 floats

  const int lane = threadIdx.x & 63;
  const int wid  = __builtin_amdgcn_readfirstlane((int)(threadIdx.x >> 6));

  // ---- prologue: coalesced W -> LDS stage -> 64 packed-f16 VGPRs per lane
  for (int i = threadIdx.x; i < O_ * 2 * C_; i += BLOCK) {
    smem[(i >> 7) * WROW + (i & 127)] = W[i];
  }
  __syncthreads();

  half2_t wp[64];                    // lane o holds W[o][0..127] as 64 f16 pairs
  {
    const float2* wrow = reinterpret_cast<const float2*>(smem + lane * WROW);
#pragma unroll                       // FULL unroll: constant indices -> registers
    for (int i = 0; i < 64; ++i) {
      const float2 f = wrow[i];
      wp[i] = __builtin_amdgcn_cvt_pkrtz(f.x, f.y);
    }
  }
  const float bl = bias[lane];
  __syncthreads();                   // everyone done reading wstage

  float* win = smem;                       // [WPB][WIN]
  float* buf = smem + WPB * WIN;           // [WPB][2*C_]
  float* mywin = win + wid * WIN;
  float* mybuf = buf + wid * 2 * C_;
  auto ldsw = (__attribute__((address_space(3))) u32*)mywin;

  // XCD<->batch partition: blocks with same blockIdx%8 land on the same XCD;
  // one batch per XCD (2 XCD-slots/batch) -> 8 MB gather working set in L2.
  const int xslot = blockIdx.x & 7;
  const int batch = xslot >> 1;                               // 0..3
  const int group = ((blockIdx.x >> 3) << 1) | (xslot & 1);   // 0..1023
  const float* xb = x + (size_t)batch * (N_ * C_);

  for (int it = 0; it < ITERS; ++it) {
    const int n = group * WPB + wid + it * 4096;        // 0..32767, exact cover
    const int p = batch * N_ + n;
    const int* arow = adj + (size_t)p * K_;             // wave-uniform -> s_load

    const float xv = xb[n * C_ + lane];

    // gather: 20 coalesced 256B rows DMA'd straight into LDS (base + lane*4)
#pragma unroll
    for (int k = 0; k < K_; ++k) {
      const int idx = arow[k];                          // SGPR
      const float* src = xb + idx * C_ + lane;
      __builtin_amdgcn_global_load_lds(
          (const __attribute__((address_space(1))) u32*)src,
          ldsw + k * C_, 4, 0, 0);
    }

    asm volatile("s_waitcnt vmcnt(0)" ::: "memory");    // per-wave DMA drain
    __builtin_amdgcn_wave_barrier();

    // window sum: lane c reads flat[20c..20c+19] as 5x float4 (16B aligned)
    const float4* wq = reinterpret_cast<const float4*>(mywin + lane * K_);
    float t = 0.f;
#pragma unroll
    for (int s = 0; s < 5; ++s) {
      const float4 v = wq[s];
      t += (v.x + v.y) + (v.z + v.w);
    }

    mybuf[lane]      = t * (1.f / K_) - xv;             // a[c]
    mybuf[C_ + lane] = xv;                              // x[c]
    asm volatile("s_waitcnt lgkmcnt(0)" ::: "memory");
    __builtin_amdgcn_wave_barrier();

    // matvec: out[o] = sum_j buf[j]*W[o][j], via v_dot2_f32_f16
    float acc0 = 0.f, acc1 = 0.f, acc2 = 0.f, acc3 = 0.f;
    const float4* bp = reinterpret_cast<const float4*>(mybuf);
#pragma unroll
    for (int i = 0; i < 32; i += 2) {
      const float4 v0 = bp[i], v1 = bp[i + 1];          // LDS broadcast reads
      const half2_t p0 = __builtin_amdgcn_cvt_pkrtz(v0.x, v0.y);
      const half2_t p1 = __builtin_amdgcn_cvt_pkrtz(v0.z, v0.w);
      const half2_t p2 = __builtin_amdgcn_cvt_pkrtz(v1.x, v1.y);
      const half2_t p3 = __builtin_amdgcn_cvt_pkrtz(v1.z, v1.w);
      acc0 = FDOT2(p0, wp[2 * i + 0], acc0);
      acc1 = FDOT2(p1, wp[2 * i + 1], acc1);
      acc2 = FDOT2(p2, wp[2 * i + 2], acc2);
      acc3 = FDOT2(p3, wp[2 * i + 3], acc3);
    }

    out[(size_t)p * O_ + lane] = ((acc0 + acc1) + (acc2 + acc3)) + bl;
  }
}

extern "C" void kernel_launch(void* const* d_in, const int* in_sizes, int n_in,
                              void* d_out, int out_size, void* d_ws, size_t ws_size,
                              hipStream_t stream) {
  const float* x    = (const float*)d_in[0];
  const int*   adj  = (const int*)d_in[1];
  const float* W    = (const float*)d_in[2];
  const float* bias = (const float*)d_in[3];
  float* out = (float*)d_out;

  hipLaunchKernelGGL(edgeconv_kernel, dim3(GRID), dim3(BLOCK), 0, stream,
                     x, adj, W, bias, out);
}

// Round 6
// 147.964 us; speedup vs baseline: 3.1780x; 1.0952x over previous
//
#include <hip/hip_runtime.h>

// EdgeConv, algebraically simplified:
//   out[p,o] = sum_c (t[p,c]/K - x[p,c])*W[o,c] + sum_c x[p,c]*W[o,64+c] + b[o]
//   t[p,c]   = sum_{k=0..19} g_flat[p, 20c+k],  g_flat[p,j] = x[b, adj[p,j>>6], j&63]
// R5: double-buffered global_load_lds pipeline (issue point it+1's 21 DMAs,
//     then s_waitcnt vmcnt(21) -> gather latency hidden behind a full iter);
//     f16 pack via one LDS round-trip (kills the 64 redundant cvts/lane);
//     persistent 768-block grid (exactly 3 blocks/CU, no quantization tail).

typedef __fp16 half2_t __attribute__((ext_vector_type(2)));
typedef unsigned int u32;

#if __has_builtin(__builtin_amdgcn_fdot2)
#define FDOT2(a, b, c) __builtin_amdgcn_fdot2((a), (b), (c), false)
#else
#define FDOT2(a, b, c) fmaf((float)((a)[0]), (float)((b)[0]), fmaf((float)((a)[1]), (float)((b)[1]), (c)))
#endif

namespace {
constexpr int N_    = 32768;
constexpr int K_    = 20;
constexpr int C_    = 64;
constexpr int O_    = 64;
constexpr int BLOCK = 256;                 // 4 waves
constexpr int WPB   = 4;
constexpr int GRID  = 768;                 // persistent: exactly 3 blocks/CU
constexpr int ROWS  = K_ + 1;              // 20 neighbor rows + center row
constexpr int WBUF  = ROWS * C_;           // 1344 floats per stage buffer
constexpr int WROW  = 132;                 // padded W row stride in LDS stage
constexpr int WAVES_PER_BATCH = (GRID / 8) * 2 * WPB;   // 768
}

__global__ __launch_bounds__(BLOCK, 3) void edgeconv_kernel(
    const float* __restrict__ x,     // (B,N,C)
    const int*   __restrict__ adj,   // (B,N,K)
    const float* __restrict__ W,     // (O, 2C)
    const float* __restrict__ bias,  // (O,)
    float*       __restrict__ out)   // (B,N,O)
{
  __shared__ __align__(16) float win2[WPB][2][WBUF];   // 43008 B (aliases wstage)
  __shared__ __align__(16) float fbuf[WPB][2 * C_];    //  2048 B
  __shared__ __align__(16) u32   hbuf[WPB][C_];        //  1024 B

  const int lane = threadIdx.x & 63;
  const int wid  = __builtin_amdgcn_readfirstlane((int)(threadIdx.x >> 6));

  // ---- prologue: coalesced W -> LDS stage -> 64 packed-f16 regs per lane
  half2_t wp[64];
  {
    float* wstage = &win2[0][0][0];                    // 33792 B < 43008 B
    for (int i = threadIdx.x; i < O_ * 2 * C_; i += BLOCK)
      wstage[(i >> 7) * WROW + (i & 127)] = W[i];
    __syncthreads();
    const float2* wrow = reinterpret_cast<const float2*>(wstage + lane * WROW);
#pragma unroll                                         // full unroll: regs, no spill
    for (int i = 0; i < 64; ++i) {
      const float2 f = wrow[i];
      wp[i] = __builtin_amdgcn_cvt_pkrtz(f.x, f.y);
    }
    __syncthreads();                                   // all waves done with wstage
  }
  const float bl = bias[lane];

  // XCD<->batch partition: blockIdx%8 -> XCD; one batch per 2 XCD slots.
  const int xslot = blockIdx.x & 7;
  const int batch = xslot >> 1;                                // 0..3
  const int group = ((blockIdx.x >> 3) << 1) | (xslot & 1);    // 0..191
  const int wv    = group * WPB + wid;                         // 0..767 in batch
  const int cnt   = (N_ - wv + WAVES_PER_BATCH - 1) / WAVES_PER_BATCH; // 42 or 43
  const float* xb   = x + (size_t)batch * (N_ * C_);
  const int*   adjb = adj + (size_t)batch * N_ * K_;

  int idx[K_];                    // uniform -> SGPRs; indices for next issue

  auto loadidx = [&](int n) {
    const int* ar = adjb + n * K_;                     // wave-uniform -> s_load
#pragma unroll
    for (int k = 0; k < K_; ++k) idx[k] = ar[k];
  };
  auto issue = [&](int n, int bsel) {
    auto ldsw = (__attribute__((address_space(3))) u32*)(&win2[wid][bsel][0]);
#pragma unroll
    for (int k = 0; k < K_; ++k) {
      const float* src = xb + idx[k] * C_ + lane;
      __builtin_amdgcn_global_load_lds(
          (const __attribute__((address_space(1))) u32*)src,
          ldsw + k * C_, 4, 0, 0);
    }
    const float* srcx = xb + n * C_ + lane;            // center row -> row 20
    __builtin_amdgcn_global_load_lds(
        (const __attribute__((address_space(1))) u32*)srcx,
        ldsw + K_ * C_, 4, 0, 0);
  };

  loadidx(wv);
  issue(wv, 0);
  if (cnt > 1) loadidx(wv + WAVES_PER_BATCH);

  for (int it = 0; it < cnt; ++it) {
    const int n   = wv + it * WAVES_PER_BATCH;
    const int cur = it & 1;

    if (it + 1 < cnt) {
      issue(n + WAVES_PER_BATCH, cur ^ 1);
      // all but the 21 just-issued DMAs are complete -> point it's data ready
      asm volatile("s_waitcnt vmcnt(21)" ::: "memory");
    } else {
      asm volatile("s_waitcnt vmcnt(0)" ::: "memory");
    }
    __builtin_amdgcn_wave_barrier();

    if (it + 2 < cnt) loadidx(wv + (it + 2) * WAVES_PER_BATCH);

    // window sum: lane c reads flat[20c..20c+19] as 5x float4 (16B aligned)
    const float* mywin = &win2[wid][cur][0];
    const float4* wq = reinterpret_cast<const float4*>(mywin + lane * K_);
    float t = 0.f;
#pragma unroll
    for (int s = 0; s < 5; ++s) {
      const float4 v = wq[s];
      t += (v.x + v.y) + (v.z + v.w);
    }
    const float xv = mywin[K_ * C_ + lane];

    // pack edge vector to f16 once (lane packs pair v[2l],v[2l+1])
    fbuf[wid][lane]      = t * (1.f / K_) - xv;        // a[c]
    fbuf[wid][C_ + lane] = xv;                         // x[c]
    const float2 pr = reinterpret_cast<const float2*>(fbuf[wid])[lane];
    hbuf[wid][lane] = __builtin_bit_cast(u32, __builtin_amdgcn_cvt_pkrtz(pr.x, pr.y));

    // matvec: out[o] = sum_j edge[j]*W[o][j] via v_dot2_f32_f16,
    // 16 broadcast ds_read_b128 + 64 fdot2
    float acc0 = 0.f, acc1 = 0.f, acc2 = 0.f, acc3 = 0.f;
    const uint4* hb = reinterpret_cast<const uint4*>(hbuf[wid]);
#pragma unroll
    for (int i = 0; i < 16; ++i) {
      const uint4 q = hb[i];
      acc0 = FDOT2(__builtin_bit_cast(half2_t, q.x), wp[4 * i + 0], acc0);
      acc1 = FDOT2(__builtin_bit_cast(half2_t, q.y), wp[4 * i + 1], acc1);
      acc2 = FDOT2(__builtin_bit_cast(half2_t, q.z), wp[4 * i + 2], acc2);
      acc3 = FDOT2(__builtin_bit_cast(half2_t, q.w), wp[4 * i + 3], acc3);
    }

    out[((size_t)batch * N_ + n) * O_ + lane] = ((acc0 + acc1) + (acc2 + acc3)) + bl;
  }
}

extern "C" void kernel_launch(void* const* d_in, const int* in_sizes, int n_in,
                              void* d_out, int out_size, void* d_ws, size_t ws_size,
                              hipStream_t stream) {
  const float* x    = (const float*)d_in[0];
  const int*   adj  = (const int*)d_in[1];
  const float* W    = (const float*)d_in[2];
  const float* bias = (const float*)d_in[3];
  float* out = (float*)d_out;

  hipLaunchKernelGGL(edgeconv_kernel, dim3(GRID), dim3(BLOCK), 0, stream,
                     x, adj, W, bias, out);
}